// Round 7
// baseline (304.648 us; speedup 1.0000x reference)
//
#include <hip/hip_runtime.h>
#include <math.h>

// QuantumNeuralNetwork: 12-qubit, 16-layer RY+CNOT-ring state-vector sim.
// Round 7: round-6 dataflow (one state per 256-thread block, 16 complex
// amps/lane, <=64 VGPR so spilling is impossible) with issue-count cuts:
//  - re/im fused in ONE 32KB float2 LDS buffer -> ds_*_b64 trips (64 ops vs
//    128 b32) and 4 barriers/layer (vs 8)
//  - slot map W (GF(2)-linear): W0=a4 W1=a5 W2=a6^a2 W3=a7^a3 W4..7=a0..3
//    W8..11=a8..11. All 4 phases: rank-4 bank-pair projection over the 6
//    within-wave lane bits -> perfect b64 bank spread. R1/W2 addresses are
//    rb | (r2<<8) -> ds offset immediates, zero addr VALU for those phases.
//  - state as 16 x float2 -> packed v_pk_fma_f32 gate math (half the VALU)
// Gate placement (identical to verified round 6):
//   L1: amp=(t<<4)|r. q8..q11 reg (r masks 8,4,2,1); q7 dpp xor1 (0xB1);
//       q6 dpp xor2 (0x4E); q5 ds_swizzle xor4 (0x101F); q4 xor8 (0x201F)
//   trip1 -> L2: amp=(r2<<8)|t. q0..q3 reg (masks 8,4,2,1)
//   trip2 -> L1 fused with CNOT-ring perm G: psi_new[a]=psi_old[G(a)],
//   G(i)=i^(i>>1)^(i&1?0xC00:0) (GF(2)-linear, verified rounds 1-6).

#define DIM     4096
#define NLAYERS 16
#define BATCH   2048
#define NCLASS  5

typedef float v2f __attribute__((ext_vector_type(2)));

__host__ __device__ constexpr unsigned gperm(unsigned i) {
  for (int q = 11; q >= 0; --q) {
    const unsigned cbit = 1u << (11 - q);
    const unsigned tbit = 1u << (11 - ((q + 1) % 12));
    if (i & cbit) i ^= tbit;
  }
  return i;
}
// slot map: W0=a4 W1=a5 W2=a6^a2 W3=a7^a3 W4..7=a0..3 W8..11=a8..11
__host__ __device__ constexpr unsigned W12(unsigned a) {
  return ((a >> 4) & 0x3u) | (((a >> 4) ^ a) & 0xCu) | ((a & 0xFu) << 4) |
         (a & 0xF00u);
}

// quad_perm DPP lane-xor (VALU): 0xB1 = xor1, 0x4E = xor2
template<int CTRL>
__device__ __forceinline__ float dppf(float x) {
  return __int_as_float(__builtin_amdgcn_update_dpp(
      0, __float_as_int(x), CTRL, 0xF, 0xF, true));
}
// ds_swizzle lane-xor (LDS pipe, no barrier): 0x101F = xor4, 0x201F = xor8
template<int PAT>
__device__ __forceinline__ float swzf(float x) {
  return __int_as_float(__builtin_amdgcn_ds_swizzle(__float_as_int(x), PAT));
}

#define FOR16(M) M(0) M(1) M(2) M(3) M(4) M(5) M(6) M(7) M(8) M(9) M(10) \
  M(11) M(12) M(13) M(14) M(15)

// packed RY pair-rotation (uses v2f locals cv, sv, nsv in scope)
#define ROT(i, j) {                                          \
    const v2f ti = p##i, tj = p##j;                          \
    p##i = __builtin_elementwise_fma(nsv, tj, cv * ti);      \
    p##j = __builtin_elementwise_fma(sv,  ti, cv * tj); }

#define GM8 ROT(0,8) ROT(1,9) ROT(2,10) ROT(3,11) ROT(4,12) ROT(5,13) \
  ROT(6,14) ROT(7,15)
#define GM4 ROT(0,4) ROT(1,5) ROT(2,6) ROT(3,7) ROT(8,12) ROT(9,13) \
  ROT(10,14) ROT(11,15)
#define GM2 ROT(0,2) ROT(1,3) ROT(4,6) ROT(5,7) ROT(8,10) ROT(9,11) \
  ROT(12,14) ROT(13,15)
#define GM1 ROT(0,1) ROT(2,3) ROT(4,5) ROT(6,7) ROT(8,9) ROT(10,11) \
  ROT(12,13) ROT(14,15)

__global__ __launch_bounds__(256)
void qnn_sim(const float* __restrict__ zr, const float* __restrict__ zi,
             const float* __restrict__ thetas, const int* __restrict__ y,
             float* __restrict__ out) {
  __shared__ v2f buf2[DIM];  // 32 KB: (re,im) per amp
  const int b = blockIdx.x;
  const int t = threadIdx.x;  // 0..255

  // layer-invariant address bases (float2 indices)
  const int w1b = (int)W12((unsigned)(t << 4));          // = (t&15)|((t<<4)&0xF00)
  const int rb  = (int)W12((unsigned)t);                 // bits 0..7 only
  const int Gt  = ((t << 4) ^ (t << 3)) & 0xFFF;         // G(t<<4)
  const int rb2 = (int)W12((unsigned)Gt);

  v2f p0,p1,p2,p3,p4,p5,p6,p7,p8,p9,p10,p11,p12,p13,p14,p15;
  {
    const float4* zr4 = (const float4*)(zr + (size_t)b * DIM + (t << 4));
    const float4* zi4 = (const float4*)(zi + (size_t)b * DIM + (t << 4));
    const float4 a0 = zr4[0], a1 = zr4[1], a2 = zr4[2], a3 = zr4[3];
    const float4 b0 = zi4[0], b1 = zi4[1], b2 = zi4[2], b3 = zi4[3];
    p0  = (v2f){a0.x, b0.x}; p1  = (v2f){a0.y, b0.y};
    p2  = (v2f){a0.z, b0.z}; p3  = (v2f){a0.w, b0.w};
    p4  = (v2f){a1.x, b1.x}; p5  = (v2f){a1.y, b1.y};
    p6  = (v2f){a1.z, b1.z}; p7  = (v2f){a1.w, b1.w};
    p8  = (v2f){a2.x, b2.x}; p9  = (v2f){a2.y, b2.y};
    p10 = (v2f){a2.z, b2.z}; p11 = (v2f){a2.w, b2.w};
    p12 = (v2f){a3.x, b3.x}; p13 = (v2f){a3.y, b3.y};
    p14 = (v2f){a3.z, b3.z}; p15 = (v2f){a3.w, b3.w};
  }

#pragma unroll 1
  for (int l = 0; l < NLAYERS; ++l) {
    const float* th = thetas + l * 12;

    // ---- L1 register gates: q8..q11 (amp bits 3..0 -> masks 8,4,2,1) ----
    { const float a = 0.5f * th[8];  const float c = __cosf(a), s = __sinf(a);
      const v2f cv = {c,c}, sv = {s,s}, nsv = {-s,-s}; GM8 }
    { const float a = 0.5f * th[9];  const float c = __cosf(a), s = __sinf(a);
      const v2f cv = {c,c}, sv = {s,s}, nsv = {-s,-s}; GM4 }
    { const float a = 0.5f * th[10]; const float c = __cosf(a), s = __sinf(a);
      const v2f cv = {c,c}, sv = {s,s}, nsv = {-s,-s}; GM2 }
    { const float a = 0.5f * th[11]; const float c = __cosf(a), s = __sinf(a);
      const v2f cv = {c,c}, sv = {s,s}, nsv = {-s,-s}; GM1 }

    // ---- DPP gates: q7 (amp bit4 = t0, xor1), q6 (amp bit5 = t1, xor2) ----
    {
      const float a7 = 0.5f * th[7];
      const float c7 = __cosf(a7), s7 = __sinf(a7);
      const float sg7 = (t & 1) ? s7 : -s7;
      const v2f cv = {c7,c7}, ssv = {sg7,sg7};
#define DPPG7(i) { v2f pr; pr.x = dppf<0xB1>(p##i.x); pr.y = dppf<0xB1>(p##i.y); \
      p##i = __builtin_elementwise_fma(ssv, pr, cv * p##i); }
      FOR16(DPPG7)
#undef DPPG7
    }
    {
      const float a6 = 0.5f * th[6];
      const float c6 = __cosf(a6), s6 = __sinf(a6);
      const float sg6 = (t & 2) ? s6 : -s6;
      const v2f cv = {c6,c6}, ssv = {sg6,sg6};
#define DPPG6(i) { v2f pr; pr.x = dppf<0x4E>(p##i.x); pr.y = dppf<0x4E>(p##i.y); \
      p##i = __builtin_elementwise_fma(ssv, pr, cv * p##i); }
      FOR16(DPPG6)
#undef DPPG6
    }

    // ---- swizzle gates: q5 (amp bit6 = t2, xor4), q4 (amp bit7 = t3, xor8)
    {
      const float a5 = 0.5f * th[5];
      const float c5 = __cosf(a5), s5 = __sinf(a5);
      const float sg5 = (t & 4) ? s5 : -s5;
      const v2f cv = {c5,c5}, ssv = {sg5,sg5};
#define SWG5(i) { v2f pr; pr.x = swzf<0x101F>(p##i.x); pr.y = swzf<0x101F>(p##i.y); \
      p##i = __builtin_elementwise_fma(ssv, pr, cv * p##i); }
      FOR16(SWG5)
#undef SWG5
    }
    {
      const float a4 = 0.5f * th[4];
      const float c4 = __cosf(a4), s4 = __sinf(a4);
      const float sg4 = (t & 8) ? s4 : -s4;
      const v2f cv = {c4,c4}, ssv = {sg4,sg4};
#define SWG4(i) { v2f pr; pr.x = swzf<0x201F>(p##i.x); pr.y = swzf<0x201F>(p##i.y); \
      p##i = __builtin_elementwise_fma(ssv, pr, cv * p##i); }
      FOR16(SWG4)
#undef SWG4
    }

    // ---- trip 1: L1 -> L2 (both components, b64) ----
    __syncthreads();  // prev layer's R2 reads done
#define W1P(i) buf2[w1b ^ ((i << 4) | (i & 0xC))] = p##i;
    FOR16(W1P)
#undef W1P
    __syncthreads();
#define R1P(i) p##i = buf2[rb + (i << 8)];
    FOR16(R1P)
#undef R1P

    // ---- L2 register gates: q0..q3 (amp bits 11..8 -> masks 8,4,2,1) ----
    { const float a = 0.5f * th[0]; const float c = __cosf(a), s = __sinf(a);
      const v2f cv = {c,c}, sv = {s,s}, nsv = {-s,-s}; GM8 }
    { const float a = 0.5f * th[1]; const float c = __cosf(a), s = __sinf(a);
      const v2f cv = {c,c}, sv = {s,s}, nsv = {-s,-s}; GM4 }
    { const float a = 0.5f * th[2]; const float c = __cosf(a), s = __sinf(a);
      const v2f cv = {c,c}, sv = {s,s}, nsv = {-s,-s}; GM2 }
    { const float a = 0.5f * th[3]; const float c = __cosf(a), s = __sinf(a);
      const v2f cv = {c,c}, sv = {s,s}, nsv = {-s,-s}; GM1 }

    // ---- trip 2: L2 -> L1 fused with CNOT-ring gather ----
    __syncthreads();  // all R1 reads done
#define W2P(i) buf2[rb + (i << 8)] = p##i;
    FOR16(W2P)
#undef W2P
    __syncthreads();
#define R2P(i) p##i = buf2[rb2 ^ (int)W12(gperm((unsigned)i))];
    FOR16(R2P)
#undef R2P
  }

  // ---- Z expectations: wire w sign = amp bit (11-w) = t bit (7-w) ----
  float P = 0.f;
#define ACC(i) P = __builtin_fmaf(p##i.x, p##i.x, P); \
               P = __builtin_fmaf(p##i.y, p##i.y, P);
  FOR16(ACC)
#undef ACC
  float e0 = ((t >> 7) & 1) ? -P : P;
  float e1 = ((t >> 6) & 1) ? -P : P;
  float e2 = ((t >> 5) & 1) ? -P : P;
  float e3 = ((t >> 4) & 1) ? -P : P;
  float e4 = ((t >> 3) & 1) ? -P : P;
#pragma unroll
  for (int off = 32; off >= 1; off >>= 1) {
    e0 += __shfl_xor(e0, off);
    e1 += __shfl_xor(e1, off);
    e2 += __shfl_xor(e2, off);
    e3 += __shfl_xor(e3, off);
    e4 += __shfl_xor(e4, off);
  }
  float* bf = (float*)buf2;
  __syncthreads();  // last R2 reads done before buf reuse
  if ((t & 63) == 0) {
    const int w8 = (t >> 6) * 8;
    bf[w8 + 0] = e0; bf[w8 + 1] = e1; bf[w8 + 2] = e2;
    bf[w8 + 3] = e3; bf[w8 + 4] = e4;
  }
  __syncthreads();
  if (t == 0) {
    const float o0 = bf[0] + bf[8]  + bf[16] + bf[24];
    const float o1 = bf[1] + bf[9]  + bf[17] + bf[25];
    const float o2 = bf[2] + bf[10] + bf[18] + bf[26];
    const float o3 = bf[3] + bf[11] + bf[19] + bf[27];
    const float o4 = bf[4] + bf[12] + bf[20] + bf[28];
    float* op = out + 1 + (size_t)b * NCLASS;
    op[0] = o0; op[1] = o1; op[2] = o2; op[3] = o3; op[4] = o4;
    // fused NLL: loss contribution = (logsumexp(o) - o[y]) / BATCH
    const float m = fmaxf(fmaxf(fmaxf(o0, o1), fmaxf(o2, o3)), o4);
    const float sum = expf(o0 - m) + expf(o1 - m) + expf(o2 - m) +
                      expf(o3 - m) + expf(o4 - m);
    const int yb = y[b];
    const float oy = (yb == 0) ? o0 : (yb == 1) ? o1 : (yb == 2) ? o2
                   : (yb == 3) ? o3 : o4;
    const float nll = (m + logf(sum)) - oy;
    atomicAdd(out, nll * (1.0f / BATCH));
  }
}

extern "C" void kernel_launch(void* const* d_in, const int* in_sizes, int n_in,
                              void* d_out, int out_size, void* d_ws, size_t ws_size,
                              hipStream_t stream) {
  const float* zr = (const float*)d_in[0];
  const float* zi = (const float*)d_in[1];
  const float* th = (const float*)d_in[2];
  const int*   y  = (const int*)d_in[3];
  float* out = (float*)d_out;
  hipMemsetAsync(out, 0, sizeof(float), stream);  // zero loss accumulator
  qnn_sim<<<BATCH, 256, 0, stream>>>(zr, zi, th, y, out);
}

// Round 8
// 273.139 us; speedup vs baseline: 1.1154x; 1.1154x over previous
//
#include <hip/hip_runtime.h>
#include <math.h>

// QuantumNeuralNetwork: 12-qubit, 16-layer RY+CNOT-ring state-vector sim.
// Round 8: merge the proven halves of rounds 6 & 7.
//  - round-7 packed gates (16 x float2 state, v_pk_fma-style math): VALU
//    busy-equiv measured 123 us (vs 198 scalar). KEEP.
//  - round-7 b64 W-map trips caused 5.9e7 bank conflicts (b64 = even/odd
//    dword phases -> 4 lanes/bank). REVERT to round-6 b32 trips with
//    f(x)=x^(x>>6) maps (measured ~0 trip conflicts), but now into TWO
//    16 KB buffers (bufR/bufI) so each phase moves both components.
//  - barriers 4->3 per layer: the R1->W2 barrier is unnecessary (W2 writes
//    exactly the addresses the same thread read in R1; per-thread address
//    sets are disjoint under the bijection -> no cross-thread hazard).
//  - q4 lane-xor8: ds_swizzle -> DPP row_ror:8 (rotate-by-8 in a 16-lane
//    row == xor8). Moves it off the LDS pipe; only q5 (xor4) stays swizzle.
// Gate placement (verified rounds 6-7):
//   L1: amp=(t<<4)|r. q8..q11 reg (masks 8,4,2,1); q7 dpp xor1 (0xB1);
//       q6 dpp xor2 (0x4E); q5 ds_swizzle xor4 (0x101F); q4 dpp row_ror:8.
//   trip1 -> L2: amp=(r2<<8)|t. q0..q3 reg (masks 8,4,2,1)
//   trip2 -> L1 fused with CNOT-ring perm G (GF(2)-linear, verified).

#define DIM     4096
#define NLAYERS 16
#define BATCH   2048
#define NCLASS  5

typedef float v2f __attribute__((ext_vector_type(2)));

__host__ __device__ constexpr unsigned gperm(unsigned i) {
  for (int q = 11; q >= 0; --q) {
    const unsigned cbit = 1u << (11 - q);
    const unsigned tbit = 1u << (11 - ((q + 1) % 12));
    if (i & cbit) i ^= tbit;
  }
  return i;
}
__host__ __device__ constexpr unsigned swz(unsigned x) { return x ^ (x >> 6); }

// DPP lane permutes (VALU): 0xB1 quad xor1, 0x4E quad xor2, 0x128 row_ror:8
template<int CTRL>
__device__ __forceinline__ float dppf(float x) {
  return __int_as_float(__builtin_amdgcn_update_dpp(
      0, __float_as_int(x), CTRL, 0xF, 0xF, true));
}
// ds_swizzle lane-xor (LDS pipe, no barrier): 0x101F = xor4
template<int PAT>
__device__ __forceinline__ float swzf(float x) {
  return __int_as_float(__builtin_amdgcn_ds_swizzle(__float_as_int(x), PAT));
}

#define FOR16(M) M(0) M(1) M(2) M(3) M(4) M(5) M(6) M(7) M(8) M(9) M(10) \
  M(11) M(12) M(13) M(14) M(15)

// packed RY pair-rotation (uses v2f locals cv, sv, nsv in scope)
#define ROT(i, j) {                                          \
    const v2f ti = p##i, tj = p##j;                          \
    p##i = __builtin_elementwise_fma(nsv, tj, cv * ti);      \
    p##j = __builtin_elementwise_fma(sv,  ti, cv * tj); }

#define GM8 ROT(0,8) ROT(1,9) ROT(2,10) ROT(3,11) ROT(4,12) ROT(5,13) \
  ROT(6,14) ROT(7,15)
#define GM4 ROT(0,4) ROT(1,5) ROT(2,6) ROT(3,7) ROT(8,12) ROT(9,13) \
  ROT(10,14) ROT(11,15)
#define GM2 ROT(0,2) ROT(1,3) ROT(4,6) ROT(5,7) ROT(8,10) ROT(9,11) \
  ROT(12,14) ROT(13,15)
#define GM1 ROT(0,1) ROT(2,3) ROT(4,5) ROT(6,7) ROT(8,9) ROT(10,11) \
  ROT(12,13) ROT(14,15)

__global__ __launch_bounds__(256)
void qnn_sim(const float* __restrict__ zr, const float* __restrict__ zi,
             const float* __restrict__ thetas, const int* __restrict__ y,
             float* __restrict__ out) {
  __shared__ float bufR[DIM];  // 16 KB real
  __shared__ float bufI[DIM];  // 16 KB imag
  const int b = blockIdx.x;
  const int t = threadIdx.x;  // 0..255

  // layer-invariant bases, f(x)=x^(x>>6) (all phases 2-way-benign, round 6)
  const int wb1 = (t << 4) ^ (t >> 2);           // f(t<<4)
  const int rb1 = t ^ (t >> 6);                  // f(t)
  const int Gt  = ((t << 4) ^ (t << 3)) & 0xFFF; // G(t<<4)
  const int rb2 = Gt ^ (Gt >> 6);                // f(G(t<<4))

  v2f p0,p1,p2,p3,p4,p5,p6,p7,p8,p9,p10,p11,p12,p13,p14,p15;
  {
    const float4* zr4 = (const float4*)(zr + (size_t)b * DIM + (t << 4));
    const float4* zi4 = (const float4*)(zi + (size_t)b * DIM + (t << 4));
    const float4 a0 = zr4[0], a1 = zr4[1], a2 = zr4[2], a3 = zr4[3];
    const float4 b0 = zi4[0], b1 = zi4[1], b2 = zi4[2], b3 = zi4[3];
    p0  = (v2f){a0.x, b0.x}; p1  = (v2f){a0.y, b0.y};
    p2  = (v2f){a0.z, b0.z}; p3  = (v2f){a0.w, b0.w};
    p4  = (v2f){a1.x, b1.x}; p5  = (v2f){a1.y, b1.y};
    p6  = (v2f){a1.z, b1.z}; p7  = (v2f){a1.w, b1.w};
    p8  = (v2f){a2.x, b2.x}; p9  = (v2f){a2.y, b2.y};
    p10 = (v2f){a2.z, b2.z}; p11 = (v2f){a2.w, b2.w};
    p12 = (v2f){a3.x, b3.x}; p13 = (v2f){a3.y, b3.y};
    p14 = (v2f){a3.z, b3.z}; p15 = (v2f){a3.w, b3.w};
  }

#pragma unroll 1
  for (int l = 0; l < NLAYERS; ++l) {
    const float* th = thetas + l * 12;

    // ---- L1 register gates: q8..q11 (amp bits 3..0 -> masks 8,4,2,1) ----
    { const float a = 0.5f * th[8];  const float c = __cosf(a), s = __sinf(a);
      const v2f cv = {c,c}, sv = {s,s}, nsv = {-s,-s}; GM8 }
    { const float a = 0.5f * th[9];  const float c = __cosf(a), s = __sinf(a);
      const v2f cv = {c,c}, sv = {s,s}, nsv = {-s,-s}; GM4 }
    { const float a = 0.5f * th[10]; const float c = __cosf(a), s = __sinf(a);
      const v2f cv = {c,c}, sv = {s,s}, nsv = {-s,-s}; GM2 }
    { const float a = 0.5f * th[11]; const float c = __cosf(a), s = __sinf(a);
      const v2f cv = {c,c}, sv = {s,s}, nsv = {-s,-s}; GM1 }

    // ---- DPP gates: q7 (t0, xor1), q6 (t1, xor2), q4 (t3, row_ror:8) ----
    {
      const float a7 = 0.5f * th[7];
      const float c7 = __cosf(a7), s7 = __sinf(a7);
      const float sg7 = (t & 1) ? s7 : -s7;
      const v2f cv = {c7,c7}, ssv = {sg7,sg7};
#define DPPG7(i) { v2f pr; pr.x = dppf<0xB1>(p##i.x); pr.y = dppf<0xB1>(p##i.y); \
      p##i = __builtin_elementwise_fma(ssv, pr, cv * p##i); }
      FOR16(DPPG7)
#undef DPPG7
    }
    {
      const float a6 = 0.5f * th[6];
      const float c6 = __cosf(a6), s6 = __sinf(a6);
      const float sg6 = (t & 2) ? s6 : -s6;
      const v2f cv = {c6,c6}, ssv = {sg6,sg6};
#define DPPG6(i) { v2f pr; pr.x = dppf<0x4E>(p##i.x); pr.y = dppf<0x4E>(p##i.y); \
      p##i = __builtin_elementwise_fma(ssv, pr, cv * p##i); }
      FOR16(DPPG6)
#undef DPPG6
    }
    {
      const float a4 = 0.5f * th[4];
      const float c4 = __cosf(a4), s4 = __sinf(a4);
      const float sg4 = (t & 8) ? s4 : -s4;
      const v2f cv = {c4,c4}, ssv = {sg4,sg4};
#define DPPG4(i) { v2f pr; pr.x = dppf<0x128>(p##i.x); pr.y = dppf<0x128>(p##i.y); \
      p##i = __builtin_elementwise_fma(ssv, pr, cv * p##i); }
      FOR16(DPPG4)
#undef DPPG4
    }

    // ---- swizzle gate: q5 (amp bit6 = t2, xor4) ----
    {
      const float a5 = 0.5f * th[5];
      const float c5 = __cosf(a5), s5 = __sinf(a5);
      const float sg5 = (t & 4) ? s5 : -s5;
      const v2f cv = {c5,c5}, ssv = {sg5,sg5};
#define SWG5(i) { v2f pr; pr.x = swzf<0x101F>(p##i.x); pr.y = swzf<0x101F>(p##i.y); \
      p##i = __builtin_elementwise_fma(ssv, pr, cv * p##i); }
      FOR16(SWG5)
#undef SWG5
    }

    // ---- trip 1: L1 -> L2 (b32, both components) ----
    __syncthreads();  // prev layer's R2 reads done
#define W1P(i) bufR[wb1 ^ i] = p##i.x; bufI[wb1 ^ i] = p##i.y;
    FOR16(W1P)
#undef W1P
    __syncthreads();
#define R1P(i) p##i.x = bufR[rb1 ^ ((i << 8) ^ (i << 2))]; \
               p##i.y = bufI[rb1 ^ ((i << 8) ^ (i << 2))];
    FOR16(R1P)
#undef R1P

    // ---- L2 register gates: q0..q3 (amp bits 11..8 -> masks 8,4,2,1) ----
    { const float a = 0.5f * th[0]; const float c = __cosf(a), s = __sinf(a);
      const v2f cv = {c,c}, sv = {s,s}, nsv = {-s,-s}; GM8 }
    { const float a = 0.5f * th[1]; const float c = __cosf(a), s = __sinf(a);
      const v2f cv = {c,c}, sv = {s,s}, nsv = {-s,-s}; GM4 }
    { const float a = 0.5f * th[2]; const float c = __cosf(a), s = __sinf(a);
      const v2f cv = {c,c}, sv = {s,s}, nsv = {-s,-s}; GM2 }
    { const float a = 0.5f * th[3]; const float c = __cosf(a), s = __sinf(a);
      const v2f cv = {c,c}, sv = {s,s}, nsv = {-s,-s}; GM1 }

    // ---- trip 2: L2 -> L1 fused with CNOT-ring gather ----
    // NO barrier before W2: each thread writes exactly the addresses it
    // read in R1 (bijective per-thread sets -> no cross-thread hazard).
#define W2P(i) bufR[rb1 ^ ((i << 8) ^ (i << 2))] = p##i.x; \
               bufI[rb1 ^ ((i << 8) ^ (i << 2))] = p##i.y;
    FOR16(W2P)
#undef W2P
    __syncthreads();
#define R2P(i) p##i.x = bufR[rb2 ^ (int)swz(gperm((unsigned)i))]; \
               p##i.y = bufI[rb2 ^ (int)swz(gperm((unsigned)i))];
    FOR16(R2P)
#undef R2P
  }

  // ---- Z expectations: wire w sign = amp bit (11-w) = t bit (7-w) ----
  float P = 0.f;
#define ACC(i) P = __builtin_fmaf(p##i.x, p##i.x, P); \
               P = __builtin_fmaf(p##i.y, p##i.y, P);
  FOR16(ACC)
#undef ACC
  float e0 = ((t >> 7) & 1) ? -P : P;
  float e1 = ((t >> 6) & 1) ? -P : P;
  float e2 = ((t >> 5) & 1) ? -P : P;
  float e3 = ((t >> 4) & 1) ? -P : P;
  float e4 = ((t >> 3) & 1) ? -P : P;
#pragma unroll
  for (int off = 32; off >= 1; off >>= 1) {
    e0 += __shfl_xor(e0, off);
    e1 += __shfl_xor(e1, off);
    e2 += __shfl_xor(e2, off);
    e3 += __shfl_xor(e3, off);
    e4 += __shfl_xor(e4, off);
  }
  __syncthreads();  // last R2 reads done before buf reuse
  if ((t & 63) == 0) {
    const int w8 = (t >> 6) * 8;
    bufR[w8 + 0] = e0; bufR[w8 + 1] = e1; bufR[w8 + 2] = e2;
    bufR[w8 + 3] = e3; bufR[w8 + 4] = e4;
  }
  __syncthreads();
  if (t == 0) {
    const float o0 = bufR[0] + bufR[8]  + bufR[16] + bufR[24];
    const float o1 = bufR[1] + bufR[9]  + bufR[17] + bufR[25];
    const float o2 = bufR[2] + bufR[10] + bufR[18] + bufR[26];
    const float o3 = bufR[3] + bufR[11] + bufR[19] + bufR[27];
    const float o4 = bufR[4] + bufR[12] + bufR[20] + bufR[28];
    float* op = out + 1 + (size_t)b * NCLASS;
    op[0] = o0; op[1] = o1; op[2] = o2; op[3] = o3; op[4] = o4;
    // fused NLL: loss contribution = (logsumexp(o) - o[y]) / BATCH
    const float m = fmaxf(fmaxf(fmaxf(o0, o1), fmaxf(o2, o3)), o4);
    const float sum = expf(o0 - m) + expf(o1 - m) + expf(o2 - m) +
                      expf(o3 - m) + expf(o4 - m);
    const int yb = y[b];
    const float oy = (yb == 0) ? o0 : (yb == 1) ? o1 : (yb == 2) ? o2
                   : (yb == 3) ? o3 : o4;
    const float nll = (m + logf(sum)) - oy;
    atomicAdd(out, nll * (1.0f / BATCH));
  }
}

extern "C" void kernel_launch(void* const* d_in, const int* in_sizes, int n_in,
                              void* d_out, int out_size, void* d_ws, size_t ws_size,
                              hipStream_t stream) {
  const float* zr = (const float*)d_in[0];
  const float* zi = (const float*)d_in[1];
  const float* th = (const float*)d_in[2];
  const int*   y  = (const int*)d_in[3];
  float* out = (float*)d_out;
  hipMemsetAsync(out, 0, sizeof(float), stream);  // zero loss accumulator
  qnn_sim<<<BATCH, 256, 0, stream>>>(zr, zi, th, y, out);
}

// Round 9
// 259.328 us; speedup vs baseline: 1.1748x; 1.0533x over previous
//
#include <hip/hip_runtime.h>
#include <math.h>

// QuantumNeuralNetwork: 12-qubit, 16-layer RY+CNOT-ring state-vector sim.
// Round 9: round-8 structure (256 thr/block, 16 complex amps/lane as float2,
// packed gates, 3 barriers/layer) with the LDS trips converted to b64 under
// a bank-proven slot map. Round 7's b64 failed because bank = dword_addr%32
// -> slot bits [3:0] must be bijective over every 16-lane group in EVERY
// phase. Map F (GF(2)-linear, bijective):
//   s[3:0] = x[7:4] ^ Q(x[3:0]),  s[7:4] = x[3:0],  s[11:8] = x[11:8]
//   Q: q0=n0^n3, q1=n1^n3, q2=n2, q3=n0   (invertible)
// Phase checks (by hand): W1 (x=(t<<4)|r): s[3:0] bijective in t[3:0] via
// identity; R1/W2 (x=(r<<8)|t): via Q; R2 (x=G((t<<4)|r)): enumerated
// t[3:0]=0..15 -> slots {0,2,3,1,6,4,5,7,C,E,F,D,A,8,9,B} all distinct.
// Every store/load of amp a goes to slot F(a) -> layouts identical to r8.
// DS issues/lane/layer: 160 -> 96 (64 b64 trips + 32 q5 swizzles); R1/W2
// addresses are pure ds-offset immediates (i<<8 float2 = i*2048 B).
// Gate placement (verified rounds 6-8):
//   L1: amp=(t<<4)|r. q8..q11 reg (masks 8,4,2,1); q7 dpp xor1 (0xB1);
//       q6 dpp xor2 (0x4E); q5 ds_swizzle xor4 (0x101F); q4 dpp row_ror:8.
//   trip1 -> L2: amp=(r<<8)|t. q0..q3 reg (masks 8,4,2,1)
//   trip2 -> L1 fused with CNOT-ring perm G(i)=i^(i>>1)^(i0?0xC00:0).

#define DIM     4096
#define NLAYERS 16
#define BATCH   2048
#define NCLASS  5

typedef float v2f __attribute__((ext_vector_type(2)));

__host__ __device__ constexpr unsigned gperm(unsigned i) {
  for (int q = 11; q >= 0; --q) {
    const unsigned cbit = 1u << (11 - q);
    const unsigned tbit = 1u << (11 - ((q + 1) % 12));
    if (i & cbit) i ^= tbit;
  }
  return i;
}
// Q and F: the bank-proven slot map (see header comment)
__host__ __device__ constexpr unsigned Qmap(unsigned lo) {
  return ((lo ^ (lo >> 3)) & 1u) | ((((lo >> 1) ^ (lo >> 3)) & 1u) << 1) |
         (((lo >> 2) & 1u) << 2) | ((lo & 1u) << 3);
}
__host__ __device__ constexpr unsigned Fmap(unsigned x) {
  return (x & 0xF00u) | ((x & 0xFu) << 4) | (((x >> 4) & 0xFu) ^ Qmap(x & 0xFu));
}

// DPP lane permutes (VALU): 0xB1 quad xor1, 0x4E quad xor2, 0x128 row_ror:8
template<int CTRL>
__device__ __forceinline__ float dppf(float x) {
  return __int_as_float(__builtin_amdgcn_update_dpp(
      0, __float_as_int(x), CTRL, 0xF, 0xF, true));
}
// ds_swizzle lane-xor (LDS pipe, no barrier): 0x101F = xor4
template<int PAT>
__device__ __forceinline__ float swzf(float x) {
  return __int_as_float(__builtin_amdgcn_ds_swizzle(__float_as_int(x), PAT));
}

#define FOR16(M) M(0) M(1) M(2) M(3) M(4) M(5) M(6) M(7) M(8) M(9) M(10) \
  M(11) M(12) M(13) M(14) M(15)

// packed RY pair-rotation (uses v2f locals cv, sv, nsv in scope)
#define ROT(i, j) {                                          \
    const v2f ti = p##i, tj = p##j;                          \
    p##i = __builtin_elementwise_fma(nsv, tj, cv * ti);      \
    p##j = __builtin_elementwise_fma(sv,  ti, cv * tj); }

#define GM8 ROT(0,8) ROT(1,9) ROT(2,10) ROT(3,11) ROT(4,12) ROT(5,13) \
  ROT(6,14) ROT(7,15)
#define GM4 ROT(0,4) ROT(1,5) ROT(2,6) ROT(3,7) ROT(8,12) ROT(9,13) \
  ROT(10,14) ROT(11,15)
#define GM2 ROT(0,2) ROT(1,3) ROT(4,6) ROT(5,7) ROT(8,10) ROT(9,11) \
  ROT(12,14) ROT(13,15)
#define GM1 ROT(0,1) ROT(2,3) ROT(4,5) ROT(6,7) ROT(8,9) ROT(10,11) \
  ROT(12,13) ROT(14,15)

__global__ __launch_bounds__(256)
void qnn_sim(const float* __restrict__ zr, const float* __restrict__ zi,
             const float* __restrict__ thetas, const int* __restrict__ y,
             float* __restrict__ out) {
  __shared__ v2f buf2[DIM];  // 32 KB: (re,im) per amp, slot = F(amp)
  const int b = blockIdx.x;
  const int t = threadIdx.x;  // 0..255

  // layer-invariant bases under F
  const int w1b = (int)((((unsigned)t & 0xF0u) << 4) | ((unsigned)t & 0xFu)); // F(t<<4)
  const int r1b = (int)Fmap((unsigned)t);                                      // F(t)
  const int Gt  = ((t << 4) ^ (t << 3)) & 0xFFF;                               // G(t<<4)
  const int r2b = (int)Fmap((unsigned)Gt);                                     // F(G(t<<4))

  v2f p0,p1,p2,p3,p4,p5,p6,p7,p8,p9,p10,p11,p12,p13,p14,p15;
  {
    const float4* zr4 = (const float4*)(zr + (size_t)b * DIM + (t << 4));
    const float4* zi4 = (const float4*)(zi + (size_t)b * DIM + (t << 4));
    const float4 a0 = zr4[0], a1 = zr4[1], a2 = zr4[2], a3 = zr4[3];
    const float4 b0 = zi4[0], b1 = zi4[1], b2 = zi4[2], b3 = zi4[3];
    p0  = (v2f){a0.x, b0.x}; p1  = (v2f){a0.y, b0.y};
    p2  = (v2f){a0.z, b0.z}; p3  = (v2f){a0.w, b0.w};
    p4  = (v2f){a1.x, b1.x}; p5  = (v2f){a1.y, b1.y};
    p6  = (v2f){a1.z, b1.z}; p7  = (v2f){a1.w, b1.w};
    p8  = (v2f){a2.x, b2.x}; p9  = (v2f){a2.y, b2.y};
    p10 = (v2f){a2.z, b2.z}; p11 = (v2f){a2.w, b2.w};
    p12 = (v2f){a3.x, b3.x}; p13 = (v2f){a3.y, b3.y};
    p14 = (v2f){a3.z, b3.z}; p15 = (v2f){a3.w, b3.w};
  }

#pragma unroll 1
  for (int l = 0; l < NLAYERS; ++l) {
    const float* th = thetas + l * 12;

    // ---- L1 register gates: q8..q11 (amp bits 3..0 -> masks 8,4,2,1) ----
    { const float a = 0.5f * th[8];  const float c = __cosf(a), s = __sinf(a);
      const v2f cv = {c,c}, sv = {s,s}, nsv = {-s,-s}; GM8 }
    { const float a = 0.5f * th[9];  const float c = __cosf(a), s = __sinf(a);
      const v2f cv = {c,c}, sv = {s,s}, nsv = {-s,-s}; GM4 }
    { const float a = 0.5f * th[10]; const float c = __cosf(a), s = __sinf(a);
      const v2f cv = {c,c}, sv = {s,s}, nsv = {-s,-s}; GM2 }
    { const float a = 0.5f * th[11]; const float c = __cosf(a), s = __sinf(a);
      const v2f cv = {c,c}, sv = {s,s}, nsv = {-s,-s}; GM1 }

    // ---- DPP gates: q7 (t0, xor1), q6 (t1, xor2), q4 (t3, row_ror:8) ----
    {
      const float a7 = 0.5f * th[7];
      const float c7 = __cosf(a7), s7 = __sinf(a7);
      const float sg7 = (t & 1) ? s7 : -s7;
      const v2f cv = {c7,c7}, ssv = {sg7,sg7};
#define DPPG7(i) { v2f pr; pr.x = dppf<0xB1>(p##i.x); pr.y = dppf<0xB1>(p##i.y); \
      p##i = __builtin_elementwise_fma(ssv, pr, cv * p##i); }
      FOR16(DPPG7)
#undef DPPG7
    }
    {
      const float a6 = 0.5f * th[6];
      const float c6 = __cosf(a6), s6 = __sinf(a6);
      const float sg6 = (t & 2) ? s6 : -s6;
      const v2f cv = {c6,c6}, ssv = {sg6,sg6};
#define DPPG6(i) { v2f pr; pr.x = dppf<0x4E>(p##i.x); pr.y = dppf<0x4E>(p##i.y); \
      p##i = __builtin_elementwise_fma(ssv, pr, cv * p##i); }
      FOR16(DPPG6)
#undef DPPG6
    }
    {
      const float a4 = 0.5f * th[4];
      const float c4 = __cosf(a4), s4 = __sinf(a4);
      const float sg4 = (t & 8) ? s4 : -s4;
      const v2f cv = {c4,c4}, ssv = {sg4,sg4};
#define DPPG4(i) { v2f pr; pr.x = dppf<0x128>(p##i.x); pr.y = dppf<0x128>(p##i.y); \
      p##i = __builtin_elementwise_fma(ssv, pr, cv * p##i); }
      FOR16(DPPG4)
#undef DPPG4
    }

    // ---- swizzle gate: q5 (amp bit6 = t2, xor4) ----
    {
      const float a5 = 0.5f * th[5];
      const float c5 = __cosf(a5), s5 = __sinf(a5);
      const float sg5 = (t & 4) ? s5 : -s5;
      const v2f cv = {c5,c5}, ssv = {sg5,sg5};
#define SWG5(i) { v2f pr; pr.x = swzf<0x101F>(p##i.x); pr.y = swzf<0x101F>(p##i.y); \
      p##i = __builtin_elementwise_fma(ssv, pr, cv * p##i); }
      FOR16(SWG5)
#undef SWG5
    }

    // ---- trip 1: L1 -> L2 (b64, slot = F(amp)) ----
    __syncthreads();  // prev layer's R2 reads done
#define W1P(i) buf2[w1b ^ (int)Fmap((unsigned)i)] = p##i;
    FOR16(W1P)
#undef W1P
    __syncthreads();
#define R1P(i) p##i = buf2[r1b + (i << 8)];
    FOR16(R1P)
#undef R1P

    // ---- L2 register gates: q0..q3 (amp bits 11..8 -> masks 8,4,2,1) ----
    { const float a = 0.5f * th[0]; const float c = __cosf(a), s = __sinf(a);
      const v2f cv = {c,c}, sv = {s,s}, nsv = {-s,-s}; GM8 }
    { const float a = 0.5f * th[1]; const float c = __cosf(a), s = __sinf(a);
      const v2f cv = {c,c}, sv = {s,s}, nsv = {-s,-s}; GM4 }
    { const float a = 0.5f * th[2]; const float c = __cosf(a), s = __sinf(a);
      const v2f cv = {c,c}, sv = {s,s}, nsv = {-s,-s}; GM2 }
    { const float a = 0.5f * th[3]; const float c = __cosf(a), s = __sinf(a);
      const v2f cv = {c,c}, sv = {s,s}, nsv = {-s,-s}; GM1 }

    // ---- trip 2: L2 -> L1 fused with CNOT-ring gather ----
    // NO barrier before W2: each thread writes exactly the addresses it
    // read in R1 (bijective per-thread sets -> no cross-thread hazard).
#define W2P(i) buf2[r1b + (i << 8)] = p##i;
    FOR16(W2P)
#undef W2P
    __syncthreads();
#define R2P(i) p##i = buf2[r2b ^ (int)Fmap(gperm((unsigned)i))];
    FOR16(R2P)
#undef R2P
  }

  // ---- Z expectations: wire w sign = amp bit (11-w) = t bit (7-w) ----
  float P = 0.f;
#define ACC(i) P = __builtin_fmaf(p##i.x, p##i.x, P); \
               P = __builtin_fmaf(p##i.y, p##i.y, P);
  FOR16(ACC)
#undef ACC
  float e0 = ((t >> 7) & 1) ? -P : P;
  float e1 = ((t >> 6) & 1) ? -P : P;
  float e2 = ((t >> 5) & 1) ? -P : P;
  float e3 = ((t >> 4) & 1) ? -P : P;
  float e4 = ((t >> 3) & 1) ? -P : P;
#pragma unroll
  for (int off = 32; off >= 1; off >>= 1) {
    e0 += __shfl_xor(e0, off);
    e1 += __shfl_xor(e1, off);
    e2 += __shfl_xor(e2, off);
    e3 += __shfl_xor(e3, off);
    e4 += __shfl_xor(e4, off);
  }
  float* bf = (float*)buf2;
  __syncthreads();  // last R2 reads done before buf reuse
  if ((t & 63) == 0) {
    const int w8 = (t >> 6) * 8;
    bf[w8 + 0] = e0; bf[w8 + 1] = e1; bf[w8 + 2] = e2;
    bf[w8 + 3] = e3; bf[w8 + 4] = e4;
  }
  __syncthreads();
  if (t == 0) {
    const float o0 = bf[0] + bf[8]  + bf[16] + bf[24];
    const float o1 = bf[1] + bf[9]  + bf[17] + bf[25];
    const float o2 = bf[2] + bf[10] + bf[18] + bf[26];
    const float o3 = bf[3] + bf[11] + bf[19] + bf[27];
    const float o4 = bf[4] + bf[12] + bf[20] + bf[28];
    float* op = out + 1 + (size_t)b * NCLASS;
    op[0] = o0; op[1] = o1; op[2] = o2; op[3] = o3; op[4] = o4;
    // fused NLL: loss contribution = (logsumexp(o) - o[y]) / BATCH
    const float m = fmaxf(fmaxf(fmaxf(o0, o1), fmaxf(o2, o3)), o4);
    const float sum = expf(o0 - m) + expf(o1 - m) + expf(o2 - m) +
                      expf(o3 - m) + expf(o4 - m);
    const int yb = y[b];
    const float oy = (yb == 0) ? o0 : (yb == 1) ? o1 : (yb == 2) ? o2
                   : (yb == 3) ? o3 : o4;
    const float nll = (m + logf(sum)) - oy;
    atomicAdd(out, nll * (1.0f / BATCH));
  }
}

extern "C" void kernel_launch(void* const* d_in, const int* in_sizes, int n_in,
                              void* d_out, int out_size, void* d_ws, size_t ws_size,
                              hipStream_t stream) {
  const float* zr = (const float*)d_in[0];
  const float* zi = (const float*)d_in[1];
  const float* th = (const float*)d_in[2];
  const int*   y  = (const int*)d_in[3];
  float* out = (float*)d_out;
  hipMemsetAsync(out, 0, sizeof(float), stream);  // zero loss accumulator
  qnn_sim<<<BATCH, 256, 0, stream>>>(zr, zi, th, y, out);
}